// Round 3
// baseline (269.443 us; speedup 1.0000x reference)
//
#include <hip/hip_runtime.h>
#include <math.h>

#define NJ 960           // tail columns (global 64..1023)
#define NSRC 896         // tail sources (global 128..1023)
#define NWARM 25

typedef unsigned long long u64;
typedef unsigned int u32;

// ws layout (u64 indices):
//   RK[896]  : tag | (rE | rI<<16)
//   CT[960]  : tag | (cntE | cntI<<16)
//   HD[960]  : tag | float bits of hd[j]
//   BSP[480] : packed pair (base[2w] | base[2w+1]<<32) — NO per-word tag;
//              ordered by DN release/acquire
//   DN[1]    : tag — DONE flag (release-published by scan)
#define RK_O 0u
#define CT_O 896u
#define HD_O 1856u
#define BSP_O 2816u
#define DN_O 3776u

#define TAG_RK 0x524B0001u
#define TAG_CT 0x43540001u
#define TAG_HD 0x48440001u
#define TAG_DN 0x444E0001u

__device__ __forceinline__ void ast(u64* p, u64 v) {
  __hip_atomic_store(p, v, __ATOMIC_RELAXED, __HIP_MEMORY_SCOPE_AGENT);
}
__device__ __forceinline__ u64 ald(const u64* p) {
  return __hip_atomic_load(p, __ATOMIC_RELAXED, __HIP_MEMORY_SCOPE_AGENT);
}
__device__ __forceinline__ u32 poll32(const u64* p, u32 tag) {
  u64 v = ald(p);
  while ((u32)(v >> 32) != tag) { __builtin_amdgcn_s_sleep(1); v = ald(p); }
  return (u32)v;
}

struct ScanSm {
  float yl[NJ];
  float2 scanE[1024];
  float2 scanI[1024];
  float4 wtot[4];
  float ssw[4];
};
struct BatSm {
  float At[64][36];     // transposed input tile (32 rows + pad)
  float Wl[16][512];    // recomputed weight tile; lane-contiguous 16B reads
  float bchl[NJ];
  float4 Ek4[64];       // {e^{+be}, e^{-be}, e^{+bi}, e^{-bi}} per head source
  float2 Ei2[64];       // raw {e_k, i_k}
};

// Fused kernel: block 0 = warmup scan; blocks 1..30 = prep prologue then batch;
// blocks 1..512 = batch (32 rows each, ONE acc[8][8], chunks sequential).
// The single base-wait sits after chunk0's MMA: chunk0 hides under the scan,
// only chunk1 (~1 GFLOP over the whole grid) runs after DN.
// launch_bounds(256,3): VGPR cap 170 >= ~140 needed -> no scratch spill;
// LDS (47.4 KB) limits to 3 blocks/CU anyway, so no occupancy loss.
__global__ __launch_bounds__(256, 3) void grn_all(
    const float* __restrict__ inp, const float* __restrict__ ident,
    const float* __restrict__ enh, const float* __restrict__ inh,
    const float* __restrict__ beta, const float* __restrict__ delta,
    void* __restrict__ wsv, float* __restrict__ out) {
  __shared__ __align__(16) char smraw[(sizeof(BatSm) > sizeof(ScanSm))
                                          ? sizeof(BatSm) : sizeof(ScanSm)];
  u64* RK = (u64*)wsv + RK_O;
  u64* CT = (u64*)wsv + CT_O;
  u64* HD = (u64*)wsv + HD_O;
  u64* BSP = (u64*)wsv + BSP_O;
  u64* DN = (u64*)wsv + DN_O;

  const int tid = threadIdx.x;
  const float bb = beta[0];
  const float dN = delta[0] / 1024.0f;

  if (blockIdx.x == 0) {
    // ---------------- scan block (proven round-7 code) ----------------
    ScanSm& S = *(ScanSm*)smraw;
    const int lane = tid & 63, wvid = tid >> 6;

    int rE[4], rI[4];
    if (tid < 224) {
      #pragma unroll
      for (int s = 0; s < 4; ++s) {
        u32 v = poll32(&RK[4 * tid + s], TAG_RK);
        rE[s] = v & 0xFFFF; rI[s] = v >> 16;
      }
    }
    int cE[4], cI[4];
    float hd[4], fm[4], fp[4];
    if (tid < 240) {
      #pragma unroll
      for (int c = 0; c < 4; ++c) {
        u32 v = poll32(&CT[4 * tid + c], TAG_CT);
        cE[c] = v & 0xFFFF; cI[c] = v >> 16;
        hd[c] = __uint_as_float(poll32(&HD[4 * tid + c], TAG_HD));
        float cj = ident[64 + 4 * tid + c];
        fm[c] = expf(-bb * cj); fp[c] = expf(bb * cj);
      }
    }
    float EP[4], EN[4], IP[4], IN2[4];
    if (tid < 224) {
      #pragma unroll
      for (int s = 0; s < 4; ++s) {
        float e = enh[128 + 4 * tid + s], i2 = inh[128 + 4 * tid + s];
        EP[s] = expf(bb * e);  EN[s] = expf(-bb * e);
        IP[s] = expf(bb * i2); IN2[s] = expf(-bb * i2);
      }
    }
    float y_own[4] = {1.0f / 1024.0f, 1.0f / 1024.0f, 1.0f / 1024.0f, 1.0f / 1024.0f};
    if (tid < 240) {
      #pragma unroll
      for (int c = 0; c < 4; ++c) S.yl[4 * tid + c] = 1.0f / 1024.0f;
    }
    __syncthreads();

    for (int t = 0; t <= NWARM; ++t) {
      if (tid == 0) {
        S.scanE[0] = make_float2(0.f, 0.f);
        S.scanI[0] = make_float2(0.f, 0.f);
      }
      if (tid >= 224) {
        #pragma unroll
        for (int c = 0; c < 4; ++c) {
          int p = 4 * tid + c;
          if (p > NSRC) {
            S.scanE[p] = make_float2(0.f, 0.f);
            S.scanI[p] = make_float2(0.f, 0.f);
          }
        }
      }
      if (tid < 224) {
        #pragma unroll
        for (int s = 0; s < 4; ++s) {
          float ym = S.yl[64 + 4 * tid + s];
          S.scanE[rE[s] + 1] = make_float2(ym * EP[s], ym * EN[s]);
          S.scanI[rI[s] + 1] = make_float2(ym * IP[s], ym * IN2[s]);
        }
      }
      __syncthreads();

      float2 e0 = S.scanE[4 * tid], e1 = S.scanE[4 * tid + 1],
             e2 = S.scanE[4 * tid + 2], e3 = S.scanE[4 * tid + 3];
      float2 i0 = S.scanI[4 * tid], i1 = S.scanI[4 * tid + 1],
             i2v = S.scanI[4 * tid + 2], i3 = S.scanI[4 * tid + 3];
      e1.x += e0.x; e1.y += e0.y; e2.x += e1.x; e2.y += e1.y; e3.x += e2.x; e3.y += e2.y;
      i1.x += i0.x; i1.y += i0.y; i2v.x += i1.x; i2v.y += i1.y; i3.x += i2v.x; i3.y += i2v.y;
      float4 tot = make_float4(e3.x, e3.y, i3.x, i3.y);
      float4 inc = tot;
      #pragma unroll
      for (int off = 1; off < 64; off <<= 1) {
        float ox = __shfl_up(inc.x, off, 64);
        float oy = __shfl_up(inc.y, off, 64);
        float oz = __shfl_up(inc.z, off, 64);
        float ow = __shfl_up(inc.w, off, 64);
        if (lane >= off) { inc.x += ox; inc.y += oy; inc.z += oz; inc.w += ow; }
      }
      if (lane == 63) S.wtot[wvid] = inc;
      __syncthreads();
      float4 exc = make_float4(inc.x - tot.x, inc.y - tot.y,
                               inc.z - tot.z, inc.w - tot.w);
      #pragma unroll
      for (int w = 0; w < 3; ++w)
        if (w < wvid) {
          float4 p = S.wtot[w];
          exc.x += p.x; exc.y += p.y; exc.z += p.z; exc.w += p.w;
        }
      e0.x += exc.x; e0.y += exc.y; e1.x += exc.x; e1.y += exc.y;
      e2.x += exc.x; e2.y += exc.y; e3.x += exc.x; e3.y += exc.y;
      i0.x += exc.z; i0.y += exc.w; i1.x += exc.z; i1.y += exc.w;
      i2v.x += exc.z; i2v.y += exc.w; i3.x += exc.z; i3.y += exc.w;
      S.scanE[4 * tid] = e0; S.scanE[4 * tid + 1] = e1;
      S.scanE[4 * tid + 2] = e2; S.scanE[4 * tid + 3] = e3;
      S.scanI[4 * tid] = i0; S.scanI[4 * tid + 1] = i1;
      S.scanI[4 * tid + 2] = i2v; S.scanI[4 * tid + 3] = i3;
      __syncthreads();

      float nv[4] = {0.f, 0.f, 0.f, 0.f};
      float psum = 0.0f;
      if (tid < 240) {
        float2 TE = S.scanE[NSRC], TI = S.scanI[NSRC];
        float pr[4];
        #pragma unroll
        for (int c = 0; c < 4; ++c) {
          float2 AE = S.scanE[cE[c]], AI = S.scanI[cI[c]];
          float dot = fm[c] * AE.x + fp[c] * (TE.y - AE.y)
                    - fm[c] * AI.x - fp[c] * (TI.y - AI.y);
          float pre = y_own[c] + dN * dot;
          pr[c] = pre;
          if (t < NWARM) {
            nv[c] = fmaxf(pre + hd[c], 0.0f);
            psum += nv[c];
          }
        }
        if (t == NWARM) {
          // packed publish: two floats per u64, no per-word tag (DN orders)
          ast(&BSP[2 * tid],
              (u64)__float_as_uint(pr[0]) | ((u64)__float_as_uint(pr[1]) << 32));
          ast(&BSP[2 * tid + 1],
              (u64)__float_as_uint(pr[2]) | ((u64)__float_as_uint(pr[3]) << 32));
        }
      }
      if (t < NWARM) {
        #pragma unroll
        for (int off = 32; off >= 1; off >>= 1) psum += __shfl_xor(psum, off);
        if (lane == 0) S.ssw[wvid] = psum;
        __syncthreads();
        float s2 = S.ssw[0] + S.ssw[1] + S.ssw[2] + S.ssw[3];
        float inv = (s2 > 0.0f) ? 1.0f / s2 : 1.0f;
        if (tid < 240) {
          #pragma unroll
          for (int c = 0; c < 4; ++c) {
            y_own[c] = nv[c] * inv;
            S.yl[4 * tid + c] = y_own[c];
          }
        }
      }
      __syncthreads();
    }
    if (tid == 0)
      __hip_atomic_store(DN, ((u64)TAG_DN << 32) | 1u, __ATOMIC_RELEASE,
                         __HIP_MEMORY_SCOPE_AGENT);
    return;
  }

  // ---------------- prep prologue (blocks 1..30) ----------------
  if (blockIdx.x <= 30) {
    const int g = (int)(blockIdx.x - 1) * 256 + tid;  // 0..7679
    const int c8 = g & 7;
    if (g < NSRC * 8) {
      int m = g >> 3;
      float myE = enh[128 + m], myI = inh[128 + m];
      int re = 0, ri = 0;
      for (int i = 112 * c8; i < 112 * c8 + 112; ++i) {
        float ev = enh[128 + i], iv = inh[128 + i];
        re += (ev < myE || (ev == myE && i < m)) ? 1 : 0;
        ri += (iv < myI || (iv == myI && i < m)) ? 1 : 0;
      }
      int p = re | (ri << 16);
      p += __shfl_xor(p, 1); p += __shfl_xor(p, 2); p += __shfl_xor(p, 4);
      if (c8 == 0) ast(&RK[m], ((u64)TAG_RK << 32) | (u32)p);
    }
    {
      int j = g >> 3;
      float cj = ident[64 + j];
      int ce = 0, ci = 0;
      for (int i = 112 * c8; i < 112 * c8 + 112; ++i) {
        ce += (enh[128 + i] <= cj) ? 1 : 0;
        ci += (inh[128 + i] <= cj) ? 1 : 0;
      }
      int p = ce | (ci << 16);
      p += __shfl_xor(p, 1); p += __shfl_xor(p, 2); p += __shfl_xor(p, 4);
      if (c8 == 0) ast(&CT[j], ((u64)TAG_CT << 32) | (u32)p);
    }
    {
      int j = g >> 3;
      float cj = ident[64 + j];
      float h = 0.0f;
      for (int k = 8 * c8; k < 8 * c8 + 8; ++k)
        h += expf(-bb * fabsf(enh[k] - cj)) - expf(-bb * fabsf(inh[k] - cj));
      h += __shfl_xor(h, 1); h += __shfl_xor(h, 2); h += __shfl_xor(h, 4);
      if (c8 == 0)
        ast(&HD[j], ((u64)TAG_HD << 32) |
                    (u64)__float_as_uint(dN * h * (1.0f / 1024.0f)));
    }
  }

  // ---------------- batch (blocks 1..512, 32 rows each) ----------------
  BatSm& Bm = *(BatSm*)smraw;
  const int colg = tid & 63;
  const int rowg = tid >> 6;
  const size_t rowbase = (size_t)(blockIdx.x - 1) * 32;

  #pragma unroll
  for (int i = 0; i < 2; ++i) {
    int fi = tid + i * 256;
    int r = fi >> 4, c4 = (fi & 15) * 4;
    float4 f4 = *(const float4*)(inp + (rowbase + r) * 64 + c4);
    Bm.At[c4 + 0][r] = f4.x; Bm.At[c4 + 1][r] = f4.y;
    Bm.At[c4 + 2][r] = f4.z; Bm.At[c4 + 3][r] = f4.w;
  }
  if (tid < 64) {
    float e = enh[tid], iv = inh[tid];
    Bm.Ek4[tid] = make_float4(expf(bb * e), expf(-bb * e),
                              expf(bb * iv), expf(-bb * iv));
    Bm.Ei2[tid] = make_float2(e, iv);
  }

  float acc[8][8];          // ONE chunk live at a time
  float rs[8];
  #pragma unroll
  for (int r = 0; r < 8; ++r) rs[r] = 0.0f;

  // Weights RECOMPUTED per chunk from the separable form:
  // exp(-b|e_k - c_j|) = (e_k >= c_j) ? e^{-b e_k} e^{+b c_j} : e^{+b e_k} e^{-b c_j}
  #pragma unroll
  for (int ch = 0; ch < 2; ++ch) {
    const int c0 = ch ? 0 : 512;          // chunk0 = cols 512..959 first
    const int jA = c0 + tid;
    const int jB = c0 + 256 + tid;
    const bool okB = (jB < NJ);
    float cjA = ident[64 + jA];
    float cjB = okB ? ident[64 + jB] : 0.0f;
    float fpA = expf(bb * cjA), fmA = expf(-bb * cjA);
    float fpB = expf(bb * cjB), fmB = expf(-bb * cjB);

    #pragma unroll
    for (int r = 0; r < 8; ++r)
      #pragma unroll
      for (int c = 0; c < 8; ++c) acc[r][c] = 0.0f;

    #pragma unroll 1
    for (int s = 0; s < 4; ++s) {
      __syncthreads();
      #pragma unroll
      for (int e = 0; e < 16; ++e) {
        int k = 16 * s + e;
        float4 E = Bm.Ek4[k];
        float2 ei = Bm.Ei2[k];
        float wA = dN * (((ei.x >= cjA) ? E.y * fpA : E.x * fmA)
                       - ((ei.y >= cjA) ? E.w * fpA : E.z * fmA));
        Bm.Wl[e][tid] = wA;
        float wB = 0.0f;
        if (okB)
          wB = dN * (((ei.x >= cjB) ? E.y * fpB : E.x * fmB)
                   - ((ei.y >= cjB) ? E.w * fpB : E.z * fmB));
        Bm.Wl[e][tid + 256] = wB;
      }
      __syncthreads();
      #pragma unroll
      for (int kk = 0; kk < 16; ++kk) {
        float4 a0 = *(const float4*)&Bm.At[16 * s + kk][rowg * 8];
        float4 a1 = *(const float4*)&Bm.At[16 * s + kk][rowg * 8 + 4];
        // lane-contiguous (16B stride) -> conflict-free ds_read_b128
        float4 w0 = *(const float4*)&Bm.Wl[kk][colg * 4];
        float4 w1 = *(const float4*)&Bm.Wl[kk][256 + colg * 4];
        float a[8] = {a0.x, a0.y, a0.z, a0.w, a1.x, a1.y, a1.z, a1.w};
        float w[8] = {w0.x, w0.y, w0.z, w0.w, w1.x, w1.y, w1.z, w1.w};
        #pragma unroll
        for (int r = 0; r < 8; ++r)
          #pragma unroll
          for (int c = 0; c < 8; ++c)
            acc[r][c] = fmaf(a[r], w[c], acc[r][c]);
      }
    }

    if (ch == 0) {
      // ---- the ONE wait: base published by scan at t==NWARM ----
      if (tid == 0) {
        u64 v = ald(DN);
        while ((u32)(v >> 32) != TAG_DN) { __builtin_amdgcn_s_sleep(32); v = ald(DN); }
        // acquire: order the packed BSP loads below after the DN observation
        (void)__hip_atomic_load(DN, __ATOMIC_ACQUIRE, __HIP_MEMORY_SCOPE_AGENT);
      }
      __syncthreads();
      if (tid < 240) {
        u64 w0 = ald(&BSP[2 * tid]);
        u64 w1 = ald(&BSP[2 * tid + 1]);
        Bm.bchl[4 * tid + 0] = __uint_as_float((u32)w0);
        Bm.bchl[4 * tid + 1] = __uint_as_float((u32)(w0 >> 32));
        Bm.bchl[4 * tid + 2] = __uint_as_float((u32)w1);
        Bm.bchl[4 * tid + 3] = __uint_as_float((u32)(w1 >> 32));
      }
      __syncthreads();
    }

    // ---- per-chunk epilogue: relu row-sum (chunk1's acc stays live) ----
    #pragma unroll
    for (int c = 0; c < 8; ++c) {
      int cl = (c < 4) ? (colg * 4 + c) : (256 + colg * 4 + (c - 4));
      int j = c0 + cl;
      float bv = (j < NJ) ? Bm.bchl[j] : -1.0e30f;  // acc is 0 there
      #pragma unroll
      for (int r = 0; r < 8; ++r)
        rs[r] += fmaxf(acc[r][c] + bv, 0.0f);
    }
  }

  #pragma unroll
  for (int r = 0; r < 8; ++r) {
    float v = rs[r];
    #pragma unroll
    for (int off = 32; off >= 1; off >>= 1) v += __shfl_xor(v, off);
    rs[r] = v;
  }
  if (colg < 16) {
    #pragma unroll
    for (int r = 0; r < 8; ++r) {
      float inv = (rs[r] > 0.0f) ? 1.0f / rs[r] : 1.0f;
      float* op = out + (rowbase + rowg * 8 + r) * 64 + colg * 4;
      float4 o;
      o.x = fmaxf(acc[r][0] + Bm.bchl[colg * 4 + 0], 0.0f) * inv;
      o.y = fmaxf(acc[r][1] + Bm.bchl[colg * 4 + 1], 0.0f) * inv;
      o.z = fmaxf(acc[r][2] + Bm.bchl[colg * 4 + 2], 0.0f) * inv;
      o.w = fmaxf(acc[r][3] + Bm.bchl[colg * 4 + 3], 0.0f) * inv;
      *(float4*)op = o;
    }
  }
}

extern "C" void kernel_launch(void* const* d_in, const int* in_sizes, int n_in,
                              void* d_out, int out_size, void* d_ws, size_t ws_size,
                              hipStream_t stream) {
  const float* inp   = (const float*)d_in[0];
  const float* ident = (const float*)d_in[1];
  const float* enh   = (const float*)d_in[2];
  const float* inh   = (const float*)d_in[3];
  const float* beta  = (const float*)d_in[4];
  const float* delta = (const float*)d_in[5];

  hipLaunchKernelGGL(grn_all, dim3(513), dim3(256), 0, stream,
                     inp, ident, enh, inh, beta, delta, d_ws, (float*)d_out);
}

// Round 4
// 171.712 us; speedup vs baseline: 1.5692x; 1.5692x over previous
//
#include <hip/hip_runtime.h>
#include <math.h>

#define NJ 960           // tail columns (global 64..1023)
#define NSRC 896         // tail sources (global 128..1023)
#define NWARM 25

typedef unsigned long long u64;
typedef unsigned int u32;

// ws layout (u64 indices):
//   RK[896]  : tag | (rE | rI<<16)
//   CT[960]  : tag | (cntE | cntI<<16)
//   HD[960]  : tag | float bits of hd[j]
//   BSP[480] : packed pair (base[2w] | base[2w+1]<<32) — ordered by DN rel/acq
//   DN[1]    : tag — DONE flag (release-published by scan)
#define RK_O 0u
#define CT_O 896u
#define HD_O 1856u
#define BSP_O 2816u
#define DN_O 3776u

#define TAG_RK 0x524B0001u
#define TAG_CT 0x43540001u
#define TAG_HD 0x48440001u
#define TAG_DN 0x444E0001u

__device__ __forceinline__ void ast(u64* p, u64 v) {
  __hip_atomic_store(p, v, __ATOMIC_RELAXED, __HIP_MEMORY_SCOPE_AGENT);
}
__device__ __forceinline__ u64 ald(const u64* p) {
  return __hip_atomic_load(p, __ATOMIC_RELAXED, __HIP_MEMORY_SCOPE_AGENT);
}
__device__ __forceinline__ u32 poll32(const u64* p, u32 tag) {
  u64 v = ald(p);
  while ((u32)(v >> 32) != tag) { __builtin_amdgcn_s_sleep(1); v = ald(p); }
  return (u32)v;
}

struct ScanSm {
  float yl[NJ];
  float2 scanE[1024];
  float2 scanI[1024];
  float4 wtot[4];
  float ssw[4];
};
struct BatSm {
  float At[64][16];     // transposed input tile (16 rows); reads are wave-broadcast
  float Wl[16][520];    // recomputed weight tile; lane-contiguous 16B reads
  float bch[NJ];
  float4 Ek4[64];       // {e^{+be}, e^{-be}, e^{+bi}, e^{-bi}} per head source
  float2 Ei2[64];       // raw {e_k, i_k}
};

// Fused kernel: block 0 = warmup scan; blocks 1..30 = prep prologue then batch;
// blocks 1..1024 = batch (16 rows each; acc for BOTH 512-col chunks live = 64
// regs/thread). Both chunk MMAs complete BEFORE the single DN wait, so only
// the epilogue (+ a one-wave block tail) runs after the scan finishes.
// (256,2): empirical VGPR cap 128; batch-path peak live ~110 -> no spill.
__global__ __launch_bounds__(256, 2) void grn_all(
    const float* __restrict__ inp, const float* __restrict__ ident,
    const float* __restrict__ enh, const float* __restrict__ inh,
    const float* __restrict__ beta, const float* __restrict__ delta,
    void* __restrict__ wsv, float* __restrict__ out) {
  __shared__ __align__(16) char smraw[(sizeof(BatSm) > sizeof(ScanSm))
                                          ? sizeof(BatSm) : sizeof(ScanSm)];
  u64* RK = (u64*)wsv + RK_O;
  u64* CT = (u64*)wsv + CT_O;
  u64* HD = (u64*)wsv + HD_O;
  u64* BSP = (u64*)wsv + BSP_O;
  u64* DN = (u64*)wsv + DN_O;

  const int tid = threadIdx.x;
  const float bb = beta[0];
  const float dN = delta[0] / 1024.0f;

  if (blockIdx.x == 0) {
    // ---------------- scan block (proven code, unchanged) ----------------
    ScanSm& S = *(ScanSm*)smraw;
    const int lane = tid & 63, wvid = tid >> 6;

    int rE[4], rI[4];
    if (tid < 224) {
      #pragma unroll
      for (int s = 0; s < 4; ++s) {
        u32 v = poll32(&RK[4 * tid + s], TAG_RK);
        rE[s] = v & 0xFFFF; rI[s] = v >> 16;
      }
    }
    int cE[4], cI[4];
    float hd[4], fm[4], fp[4];
    if (tid < 240) {
      #pragma unroll
      for (int c = 0; c < 4; ++c) {
        u32 v = poll32(&CT[4 * tid + c], TAG_CT);
        cE[c] = v & 0xFFFF; cI[c] = v >> 16;
        hd[c] = __uint_as_float(poll32(&HD[4 * tid + c], TAG_HD));
        float cj = ident[64 + 4 * tid + c];
        fm[c] = expf(-bb * cj); fp[c] = expf(bb * cj);
      }
    }
    float EP[4], EN[4], IP[4], IN2[4];
    if (tid < 224) {
      #pragma unroll
      for (int s = 0; s < 4; ++s) {
        float e = enh[128 + 4 * tid + s], i2 = inh[128 + 4 * tid + s];
        EP[s] = expf(bb * e);  EN[s] = expf(-bb * e);
        IP[s] = expf(bb * i2); IN2[s] = expf(-bb * i2);
      }
    }
    float y_own[4] = {1.0f / 1024.0f, 1.0f / 1024.0f, 1.0f / 1024.0f, 1.0f / 1024.0f};
    if (tid < 240) {
      #pragma unroll
      for (int c = 0; c < 4; ++c) S.yl[4 * tid + c] = 1.0f / 1024.0f;
    }
    __syncthreads();

    for (int t = 0; t <= NWARM; ++t) {
      if (tid == 0) {
        S.scanE[0] = make_float2(0.f, 0.f);
        S.scanI[0] = make_float2(0.f, 0.f);
      }
      if (tid >= 224) {
        #pragma unroll
        for (int c = 0; c < 4; ++c) {
          int p = 4 * tid + c;
          if (p > NSRC) {
            S.scanE[p] = make_float2(0.f, 0.f);
            S.scanI[p] = make_float2(0.f, 0.f);
          }
        }
      }
      if (tid < 224) {
        #pragma unroll
        for (int s = 0; s < 4; ++s) {
          float ym = S.yl[64 + 4 * tid + s];
          S.scanE[rE[s] + 1] = make_float2(ym * EP[s], ym * EN[s]);
          S.scanI[rI[s] + 1] = make_float2(ym * IP[s], ym * IN2[s]);
        }
      }
      __syncthreads();

      float2 e0 = S.scanE[4 * tid], e1 = S.scanE[4 * tid + 1],
             e2 = S.scanE[4 * tid + 2], e3 = S.scanE[4 * tid + 3];
      float2 i0 = S.scanI[4 * tid], i1 = S.scanI[4 * tid + 1],
             i2v = S.scanI[4 * tid + 2], i3 = S.scanI[4 * tid + 3];
      e1.x += e0.x; e1.y += e0.y; e2.x += e1.x; e2.y += e1.y; e3.x += e2.x; e3.y += e2.y;
      i1.x += i0.x; i1.y += i0.y; i2v.x += i1.x; i2v.y += i1.y; i3.x += i2v.x; i3.y += i2v.y;
      float4 tot = make_float4(e3.x, e3.y, i3.x, i3.y);
      float4 inc = tot;
      #pragma unroll
      for (int off = 1; off < 64; off <<= 1) {
        float ox = __shfl_up(inc.x, off, 64);
        float oy = __shfl_up(inc.y, off, 64);
        float oz = __shfl_up(inc.z, off, 64);
        float ow = __shfl_up(inc.w, off, 64);
        if (lane >= off) { inc.x += ox; inc.y += oy; inc.z += oz; inc.w += ow; }
      }
      if (lane == 63) S.wtot[wvid] = inc;
      __syncthreads();
      float4 exc = make_float4(inc.x - tot.x, inc.y - tot.y,
                               inc.z - tot.z, inc.w - tot.w);
      #pragma unroll
      for (int w = 0; w < 3; ++w)
        if (w < wvid) {
          float4 p = S.wtot[w];
          exc.x += p.x; exc.y += p.y; exc.z += p.z; exc.w += p.w;
        }
      e0.x += exc.x; e0.y += exc.y; e1.x += exc.x; e1.y += exc.y;
      e2.x += exc.x; e2.y += exc.y; e3.x += exc.x; e3.y += exc.y;
      i0.x += exc.z; i0.y += exc.w; i1.x += exc.z; i1.y += exc.w;
      i2v.x += exc.z; i2v.y += exc.w; i3.x += exc.z; i3.y += exc.w;
      S.scanE[4 * tid] = e0; S.scanE[4 * tid + 1] = e1;
      S.scanE[4 * tid + 2] = e2; S.scanE[4 * tid + 3] = e3;
      S.scanI[4 * tid] = i0; S.scanI[4 * tid + 1] = i1;
      S.scanI[4 * tid + 2] = i2v; S.scanI[4 * tid + 3] = i3;
      __syncthreads();

      float nv[4] = {0.f, 0.f, 0.f, 0.f};
      float psum = 0.0f;
      if (tid < 240) {
        float2 TE = S.scanE[NSRC], TI = S.scanI[NSRC];
        float pr[4];
        #pragma unroll
        for (int c = 0; c < 4; ++c) {
          float2 AE = S.scanE[cE[c]], AI = S.scanI[cI[c]];
          float dot = fm[c] * AE.x + fp[c] * (TE.y - AE.y)
                    - fm[c] * AI.x - fp[c] * (TI.y - AI.y);
          float pre = y_own[c] + dN * dot;
          pr[c] = pre;
          if (t < NWARM) {
            nv[c] = fmaxf(pre + hd[c], 0.0f);
            psum += nv[c];
          }
        }
        if (t == NWARM) {
          ast(&BSP[2 * tid],
              (u64)__float_as_uint(pr[0]) | ((u64)__float_as_uint(pr[1]) << 32));
          ast(&BSP[2 * tid + 1],
              (u64)__float_as_uint(pr[2]) | ((u64)__float_as_uint(pr[3]) << 32));
        }
      }
      if (t < NWARM) {
        #pragma unroll
        for (int off = 32; off >= 1; off >>= 1) psum += __shfl_xor(psum, off);
        if (lane == 0) S.ssw[wvid] = psum;
        __syncthreads();
        float s2 = S.ssw[0] + S.ssw[1] + S.ssw[2] + S.ssw[3];
        float inv = (s2 > 0.0f) ? 1.0f / s2 : 1.0f;
        if (tid < 240) {
          #pragma unroll
          for (int c = 0; c < 4; ++c) {
            y_own[c] = nv[c] * inv;
            S.yl[4 * tid + c] = y_own[c];
          }
        }
      }
      __syncthreads();
    }
    if (tid == 0)
      __hip_atomic_store(DN, ((u64)TAG_DN << 32) | 1u, __ATOMIC_RELEASE,
                         __HIP_MEMORY_SCOPE_AGENT);
    return;
  }

  // ---------------- prep prologue (blocks 1..30) ----------------
  if (blockIdx.x <= 30) {
    const int g = (int)(blockIdx.x - 1) * 256 + tid;  // 0..7679
    const int c8 = g & 7;
    if (g < NSRC * 8) {
      int m = g >> 3;
      float myE = enh[128 + m], myI = inh[128 + m];
      int re = 0, ri = 0;
      for (int i = 112 * c8; i < 112 * c8 + 112; ++i) {
        float ev = enh[128 + i], iv = inh[128 + i];
        re += (ev < myE || (ev == myE && i < m)) ? 1 : 0;
        ri += (iv < myI || (iv == myI && i < m)) ? 1 : 0;
      }
      int p = re | (ri << 16);
      p += __shfl_xor(p, 1); p += __shfl_xor(p, 2); p += __shfl_xor(p, 4);
      if (c8 == 0) ast(&RK[m], ((u64)TAG_RK << 32) | (u32)p);
    }
    {
      int j = g >> 3;
      float cj = ident[64 + j];
      int ce = 0, ci = 0;
      for (int i = 112 * c8; i < 112 * c8 + 112; ++i) {
        ce += (enh[128 + i] <= cj) ? 1 : 0;
        ci += (inh[128 + i] <= cj) ? 1 : 0;
      }
      int p = ce | (ci << 16);
      p += __shfl_xor(p, 1); p += __shfl_xor(p, 2); p += __shfl_xor(p, 4);
      if (c8 == 0) ast(&CT[j], ((u64)TAG_CT << 32) | (u32)p);
    }
    {
      int j = g >> 3;
      float cj = ident[64 + j];
      float h = 0.0f;
      for (int k = 8 * c8; k < 8 * c8 + 8; ++k)
        h += expf(-bb * fabsf(enh[k] - cj)) - expf(-bb * fabsf(inh[k] - cj));
      h += __shfl_xor(h, 1); h += __shfl_xor(h, 2); h += __shfl_xor(h, 4);
      if (c8 == 0)
        ast(&HD[j], ((u64)TAG_HD << 32) |
                    (u64)__float_as_uint(dN * h * (1.0f / 1024.0f)));
    }
  }

  // ---------------- batch (blocks 1..1024, 16 rows each) ----------------
  BatSm& Bm = *(BatSm*)smraw;
  const int colg = tid & 63;
  const int rowg = tid >> 6;             // wave id == row group (4 rows each)
  const size_t rowbase = (size_t)(blockIdx.x - 1) * 16;

  {
    int r = tid >> 4, c4 = (tid & 15) * 4;
    float4 f4 = *(const float4*)(inp + (rowbase + r) * 64 + c4);
    Bm.At[c4 + 0][r] = f4.x; Bm.At[c4 + 1][r] = f4.y;
    Bm.At[c4 + 2][r] = f4.z; Bm.At[c4 + 3][r] = f4.w;
  }
  if (tid < 64) {
    float e = enh[tid], iv = inh[tid];
    Bm.Ek4[tid] = make_float4(expf(bb * e), expf(-bb * e),
                              expf(bb * iv), expf(-bb * iv));
    Bm.Ei2[tid] = make_float2(e, iv);
  }

  float acc0[4][8], acc1[4][8];          // both chunks live: 64 regs total
  #pragma unroll
  for (int r = 0; r < 4; ++r)
    #pragma unroll
    for (int c = 0; c < 8; ++c) { acc0[r][c] = 0.0f; acc1[r][c] = 0.0f; }

  // Weights recomputed from the separable form:
  // exp(-b|e_k - c_j|) = (e_k >= c_j) ? e^{-b e_k} e^{+b c_j} : e^{+b e_k} e^{-b c_j}
  // #pragma unroll 4 on staging: caps live LDS-load temporaries (spill fix).

  {  // ---- chunk 0: cols 0..511 ----
    const float cjA = ident[64 + tid];
    const float cjB = ident[64 + 256 + tid];
    const float fpA = expf(bb * cjA), fmA = expf(-bb * cjA);
    const float fpB = expf(bb * cjB), fmB = expf(-bb * cjB);
    #pragma unroll 1
    for (int s = 0; s < 4; ++s) {
      __syncthreads();
      #pragma unroll 4
      for (int e = 0; e < 16; ++e) {
        int k = 16 * s + e;
        float4 E = Bm.Ek4[k];
        float2 ei = Bm.Ei2[k];
        Bm.Wl[e][tid] = dN * (((ei.x >= cjA) ? E.y * fpA : E.x * fmA)
                            - ((ei.y >= cjA) ? E.w * fpA : E.z * fmA));
        Bm.Wl[e][tid + 256] = dN * (((ei.x >= cjB) ? E.y * fpB : E.x * fmB)
                                  - ((ei.y >= cjB) ? E.w * fpB : E.z * fmB));
      }
      __syncthreads();
      #pragma unroll
      for (int kk = 0; kk < 16; ++kk) {
        float4 av = *(const float4*)&Bm.At[16 * s + kk][rowg * 4];  // broadcast
        float4 w0 = *(const float4*)&Bm.Wl[kk][colg * 4];
        float4 w1 = *(const float4*)&Bm.Wl[kk][256 + colg * 4];
        float a_[4] = {av.x, av.y, av.z, av.w};
        float w_[8] = {w0.x, w0.y, w0.z, w0.w, w1.x, w1.y, w1.z, w1.w};
        #pragma unroll
        for (int r = 0; r < 4; ++r)
          #pragma unroll
          for (int c = 0; c < 8; ++c)
            acc0[r][c] = fmaf(a_[r], w_[c], acc0[r][c]);
      }
    }
  }

  {  // ---- chunk 1: cols 512..959 (tail guarded) ----
    const float cjA = ident[64 + 512 + tid];
    const bool okB = (768 + tid) < NJ;   // tid < 192
    const float cjB = okB ? ident[64 + 768 + tid] : 0.0f;
    const float fpA = expf(bb * cjA), fmA = expf(-bb * cjA);
    const float fpB = expf(bb * cjB), fmB = expf(-bb * cjB);
    #pragma unroll 1
    for (int s = 0; s < 4; ++s) {
      __syncthreads();
      #pragma unroll 4
      for (int e = 0; e < 16; ++e) {
        int k = 16 * s + e;
        float4 E = Bm.Ek4[k];
        float2 ei = Bm.Ei2[k];
        Bm.Wl[e][tid] = dN * (((ei.x >= cjA) ? E.y * fpA : E.x * fmA)
                            - ((ei.y >= cjA) ? E.w * fpA : E.z * fmA));
        float wB = 0.0f;
        if (okB)
          wB = dN * (((ei.x >= cjB) ? E.y * fpB : E.x * fmB)
                   - ((ei.y >= cjB) ? E.w * fpB : E.z * fmB));
        Bm.Wl[e][tid + 256] = wB;
      }
      __syncthreads();
      #pragma unroll
      for (int kk = 0; kk < 16; ++kk) {
        float4 av = *(const float4*)&Bm.At[16 * s + kk][rowg * 4];  // broadcast
        float4 w0 = *(const float4*)&Bm.Wl[kk][colg * 4];
        float4 w1 = *(const float4*)&Bm.Wl[kk][256 + colg * 4];
        float a_[4] = {av.x, av.y, av.z, av.w};
        float w_[8] = {w0.x, w0.y, w0.z, w0.w, w1.x, w1.y, w1.z, w1.w};
        #pragma unroll
        for (int r = 0; r < 4; ++r)
          #pragma unroll
          for (int c = 0; c < 8; ++c)
            acc1[r][c] = fmaf(a_[r], w_[c], acc1[r][c]);
      }
    }
  }

  // ---- the ONE wait: base published by scan at t==NWARM ----
  if (tid == 0) {
    u64 v = ald(DN);
    while ((u32)(v >> 32) != TAG_DN) { __builtin_amdgcn_s_sleep(32); v = ald(DN); }
    (void)__hip_atomic_load(DN, __ATOMIC_ACQUIRE, __HIP_MEMORY_SCOPE_AGENT);
  }
  __syncthreads();
  if (tid < 240) {
    u64 w0 = ald(&BSP[2 * tid]);
    u64 w1 = ald(&BSP[2 * tid + 1]);
    Bm.bch[4 * tid + 0] = __uint_as_float((u32)w0);
    Bm.bch[4 * tid + 1] = __uint_as_float((u32)(w0 >> 32));
    Bm.bch[4 * tid + 2] = __uint_as_float((u32)w1);
    Bm.bch[4 * tid + 3] = __uint_as_float((u32)(w1 >> 32));
  }
  __syncthreads();

  // ---- epilogue: relu row-sums over both chunks, then normalize+store ----
  float rs[4] = {0.f, 0.f, 0.f, 0.f};
  #pragma unroll
  for (int c = 0; c < 8; ++c) {
    int cl = (c < 4) ? (colg * 4 + c) : (256 + colg * 4 + (c - 4));
    float bv0 = Bm.bch[cl];
    int j1 = 512 + cl;
    float bv1 = (j1 < NJ) ? Bm.bch[j1] : -1.0e30f;  // acc1 is 0 there
    #pragma unroll
    for (int r = 0; r < 4; ++r) {
      rs[r] += fmaxf(acc0[r][c] + bv0, 0.0f);
      rs[r] += fmaxf(acc1[r][c] + bv1, 0.0f);
    }
  }
  #pragma unroll
  for (int r = 0; r < 4; ++r) {
    float v = rs[r];
    #pragma unroll
    for (int off = 32; off >= 1; off >>= 1) v += __shfl_xor(v, off);
    rs[r] = v;
  }
  if (colg < 16) {
    #pragma unroll
    for (int r = 0; r < 4; ++r) {
      float inv = (rs[r] > 0.0f) ? 1.0f / rs[r] : 1.0f;
      float* op = out + (rowbase + rowg * 4 + r) * 64 + colg * 4;
      float4 o;
      o.x = fmaxf(acc0[r][0] + Bm.bch[colg * 4 + 0], 0.0f) * inv;
      o.y = fmaxf(acc0[r][1] + Bm.bch[colg * 4 + 1], 0.0f) * inv;
      o.z = fmaxf(acc0[r][2] + Bm.bch[colg * 4 + 2], 0.0f) * inv;
      o.w = fmaxf(acc0[r][3] + Bm.bch[colg * 4 + 3], 0.0f) * inv;
      *(float4*)op = o;
    }
  }
}

extern "C" void kernel_launch(void* const* d_in, const int* in_sizes, int n_in,
                              void* d_out, int out_size, void* d_ws, size_t ws_size,
                              hipStream_t stream) {
  const float* inp   = (const float*)d_in[0];
  const float* ident = (const float*)d_in[1];
  const float* enh   = (const float*)d_in[2];
  const float* inh   = (const float*)d_in[3];
  const float* beta  = (const float*)d_in[4];
  const float* delta = (const float*)d_in[5];

  hipLaunchKernelGGL(grn_all, dim3(1025), dim3(256), 0, stream,
                     inp, ident, enh, inh, beta, delta, d_ws, (float*)d_out);
}